// Round 2
// baseline (991.518 us; speedup 1.0000x reference)
//
#include <hip/hip_runtime.h>

#define F 128

typedef __attribute__((ext_vector_type(8))) short bf16x8;
typedef __attribute__((ext_vector_type(4))) float f32x4;

// ---------- helpers ----------

// software RNE f32->bf16 (kept for prep_weights so weight bits are unchanged)
__device__ __forceinline__ short f2bf(float f) {
  union { float f; unsigned u; } v; v.f = f;
  unsigned r = (v.u + 0x7FFFu + ((v.u >> 16) & 1u)) >> 16;  // RNE
  return (short)r;
}

// hardware packed f32->bf16 (RNE), 1 VALU op for 2 converts
__device__ __forceinline__ unsigned cvt_pk_bf16(float a, float b) {
  unsigned d;
  asm("v_cvt_pk_bf16_f32 %0, %1, %2" : "=v"(d) : "v"(a), "v"(b));
  return d;
}

// shifted softplus: softplus(x) - ln(2), numerically stable
__device__ __forceinline__ float sspf(float x) {
  float t = __expf(-fabsf(x));
  return fmaxf(x, 0.0f) + __logf(1.0f + t) - 0.69314718055994530942f;
}

// H/C staging in LDS: 128 rows x 128 bf16, XOR-swizzled in 8-short (16B) chunks
// so that b16 scatter-writes and b128 A-frag reads are both ~conflict-free.
__device__ __forceinline__ int h_idx(int row, int k) {
  int chunk = k >> 3;
  int sw = chunk ^ (row & 15);
  return row * 128 + sw * 8 + (k & 7);
}

// wf half-buffer: 64 rows x 128 f32, bit-4 XOR swizzle breaks the 4-quad conflict
__device__ __forceinline__ int wfb_idx(int row, int c) {
  return row * 128 + (c ^ ((row & 4) << 2));
}

// B-fragment load straight from global frag-ordered weight (L1/L2-hot, coalesced 16B/lane)
__device__ __forceinline__ bf16x8 load_bfrag_g(const unsigned short* __restrict__ W,
                                               int nt, int kb, int lane) {
  return *(const bf16x8*)(W + (((nt * 4 + kb) * 64 + lane) << 3));
}

// A-fragment from row-major fp32 global: 8 consecutive floats -> 8 bf16 (hw cvt_pk)
__device__ __forceinline__ bf16x8 load_afrag_f32(const float* __restrict__ p, bool valid) {
  union { bf16x8 v; unsigned u[4]; } r;
  if (valid) {
    const float4* q = (const float4*)p;
    float4 x0 = q[0], x1 = q[1];
    r.u[0] = cvt_pk_bf16(x0.x, x0.y);
    r.u[1] = cvt_pk_bf16(x0.z, x0.w);
    r.u[2] = cvt_pk_bf16(x1.x, x1.y);
    r.u[3] = cvt_pk_bf16(x1.z, x1.w);
  } else {
    r.u[0] = r.u[1] = r.u[2] = r.u[3] = 0u;
  }
  return r.v;
}

// ---------- prep: convert 5 weight matrices to bf16 MFMA-B-fragment order ----------
// B-frag layout for W[k][n] (128x128): frag(nt,kb), lane = ((k>>3)&3)<<4 | (n&15), j = k&7
__global__ void prep_weights(const float* __restrict__ W1, const float* __restrict__ W2,
                             const float* __restrict__ Wi2f, const float* __restrict__ Wf2o,
                             const float* __restrict__ Wd, unsigned short* __restrict__ out) {
  int t = blockIdx.x * 256 + threadIdx.x;  // 5*16384 total
  int m = t >> 14;
  int idx = t & 16383;
  int k = idx >> 7, n = idx & 127;
  const float* W = (m == 0) ? W1 : (m == 1) ? W2 : (m == 2) ? Wi2f : (m == 3) ? Wf2o : Wd;
  float v = W[idx];
  int nt = n >> 4, kb = k >> 5;
  int lane = (((k >> 3) & 3) << 4) | (n & 15);
  int j = k & 7;
  int dst = (((nt * 4 + kb) * 64 + lane) << 3) | j;
  out[(m << 14) + dst] = (unsigned short)f2bf(v);
}

// ---------- f = x @ W_in2fac  (no bias, no activation; no LDS, no syncs) ----------
__global__ __launch_bounds__(256, 4) void f_kernel(const float* __restrict__ x,
                                                   const unsigned short* __restrict__ wfrag,
                                                   float* __restrict__ f, int N) {
  const int tid = threadIdx.x;
  const int lane = tid & 63, wv = tid >> 6;
  const int quad = lane >> 4, ln = lane & 15;
  const int r0 = blockIdx.x * 128;
  const unsigned short* Wf = wfrag + 2 * 16384;

  bf16x8 a1[2][4];
#pragma unroll
  for (int mt = 0; mt < 2; ++mt) {
    int row = r0 + wv * 32 + mt * 16 + ln;
    bool valid = row < N;
    const float* rp = x + (size_t)row * F + quad * 8;
#pragma unroll
    for (int kb = 0; kb < 4; ++kb) a1[mt][kb] = load_afrag_f32(rp + kb * 32, valid);
  }

#pragma unroll
  for (int nt = 0; nt < 8; ++nt) {
    f32x4 acc0 = {0, 0, 0, 0}, acc1 = {0, 0, 0, 0};
#pragma unroll
    for (int kb = 0; kb < 4; ++kb) {
      bf16x8 b = load_bfrag_g(Wf, nt, kb, lane);
      acc0 = __builtin_amdgcn_mfma_f32_16x16x32_bf16(a1[0][kb], b, acc0, 0, 0, 0);
      acc1 = __builtin_amdgcn_mfma_f32_16x16x32_bf16(a1[1][kb], b, acc1, 0, 0, 0);
    }
    int col = nt * 16 + ln;
#pragma unroll
    for (int mt = 0; mt < 2; ++mt) {
#pragma unroll
      for (int r = 0; r < 4; ++r) {
        int row = r0 + wv * 32 + mt * 16 + quad * 4 + r;
        if (row < N) f[(size_t)row * F + col] = (mt == 0) ? acc0[r] : acc1[r];
      }
    }
  }
}

// ---------- fused edge pipeline ----------
// h = ssp(dijk@W1+b1); w = ssp(h@W2+b2); (seg_j = arange -> identity)
// wf = w * f[idx_j]; conv[seg_i] += wf  (seg_i sorted -> run-length reduce + atomics)
// LDS: 32KB union {H bf16 128x128 | wf f32 64x128 half-tile} -> 4 blocks/CU
// GEMM2 is split into two mt-passes so only wreg[8][4] (32 f32) is live at a
// time: round-1's single-pass version kept wreg[2][8][4] (64 f32) live across
// the flow, overflowed the 128-VGPR cap (compiler allocated 64 + scratch) and
// spilled ~410MB/launch to HBM (FETCH +164MB, WRITE +335MB).
__global__ __launch_bounds__(256, 4) void edge_kernel(
    const float* __restrict__ dijk, const int* __restrict__ idx_j, const int* __restrict__ seg_i,
    const float* __restrict__ b1, const float* __restrict__ b2,
    const unsigned short* __restrict__ wfrag, const float* __restrict__ f,
    float* __restrict__ conv, int E) {
  __shared__ union { short s[16384]; float fl[8192]; } sm;  // 32KB
  __shared__ int sIdx[128];
  __shared__ int sSeg[128];

  const int tid = threadIdx.x;
  const int lane = tid & 63, wv = tid >> 6;
  const int quad = lane >> 4, ln = lane & 15;
  const int e0 = blockIdx.x * 128;
  const unsigned short* W1f = wfrag;
  const unsigned short* W2f = wfrag + 16384;

  if (tid < 128) {
    int e = e0 + tid;
    sIdx[tid] = (e < E) ? idx_j[e] : 0;
    sSeg[tid] = (e < E) ? seg_i[e] : -1;
  }

  float bias1v[8], bias2v[8];
#pragma unroll
  for (int nt = 0; nt < 8; ++nt) {
    bias1v[nt] = b1[nt * 16 + ln];
    bias2v[nt] = b2[nt * 16 + ln];
  }

  // A1 frags straight from global dijk (each wave owns 32 edge rows)
  bf16x8 a1[2][4];
#pragma unroll
  for (int mt = 0; mt < 2; ++mt) {
    int row = e0 + wv * 32 + mt * 16 + ln;
    bool valid = row < E;
    const float* rp = dijk + (size_t)row * F + quad * 8;
#pragma unroll
    for (int kb = 0; kb < 4; ++kb) a1[mt][kb] = load_afrag_f32(rp + kb * 32, valid);
  }

  // GEMM1 (B-frags from global) -> ssp -> bf16 -> sH directly
  short* sH = sm.s;
#pragma unroll
  for (int nt = 0; nt < 8; ++nt) {
    f32x4 acc0 = {0, 0, 0, 0}, acc1 = {0, 0, 0, 0};
#pragma unroll
    for (int kb = 0; kb < 4; ++kb) {
      bf16x8 b = load_bfrag_g(W1f, nt, kb, lane);
      acc0 = __builtin_amdgcn_mfma_f32_16x16x32_bf16(a1[0][kb], b, acc0, 0, 0, 0);
      acc1 = __builtin_amdgcn_mfma_f32_16x16x32_bf16(a1[1][kb], b, acc1, 0, 0, 0);
    }
    int c = nt * 16 + ln;
#pragma unroll
    for (int r = 0; r < 4; ++r) {
      sH[h_idx(wv * 32 + quad * 4 + r, c)] =
          (short)cvt_pk_bf16(sspf(acc0[r] + bias1v[nt]), 0.0f);
      sH[h_idx(wv * 32 + 16 + quad * 4 + r, c)] =
          (short)cvt_pk_bf16(sspf(acc1[r] + bias1v[nt]), 0.0f);
    }
  }
  __syncthreads();

  // GEMM2 A frags from staged H (both halves up front; sH dies after this)
  bf16x8 a2[2][4];
#pragma unroll
  for (int mt = 0; mt < 2; ++mt) {
    int row = wv * 32 + mt * 16 + ln;
#pragma unroll
    for (int kb = 0; kb < 4; ++kb)
      a2[mt][kb] = *(const bf16x8*)(sH + h_idx(row, kb * 32 + quad * 8));
  }

  // Two passes over mt: GEMM2 -> ssp -> *f[idx_j] -> wf half-tile -> reduce.
  // Only 32 f32 of w-state live per pass. Run-length merging across the
  // 16-row gaps in each thread's row set is fine: addition into conv[seg]
  // is order/partition independent.
  float* sWF = sm.fl;
#pragma unroll
  for (int half = 0; half < 2; ++half) {
    // GEMM2 pass (registers + global B-frags only; no LDS traffic)
    float wreg[8][4];
#pragma unroll
    for (int nt = 0; nt < 8; ++nt) {
      f32x4 acc = {0, 0, 0, 0};
#pragma unroll
      for (int kb = 0; kb < 4; ++kb) {
        bf16x8 b = load_bfrag_g(W2f, nt, kb, lane);
        acc = __builtin_amdgcn_mfma_f32_16x16x32_bf16(a2[half][kb], b, acc, 0, 0, 0);
      }
#pragma unroll
      for (int r = 0; r < 4; ++r) wreg[nt][r] = sspf(acc[r] + bias2v[nt]);
    }

    // half==0: prior readers of the sm region are the a2 loads above;
    // half==1: prior readers are half-0's reduction. Either way, barrier
    // sits after ~32 reg-only MFMAs, which absorb straggler latency.
    __syncthreads();

#pragma unroll
    for (int r = 0; r < 4; ++r) {
      int lr = quad * 4 + r;
      int brow = wv * 16 + lr;
      int erow = wv * 32 + half * 16 + lr;
      int jrow = sIdx[erow];
      const float* fp = f + (size_t)jrow * F;
#pragma unroll
      for (int nt = 0; nt < 8; ++nt) {
        int c = nt * 16 + ln;
        sWF[wfb_idx(brow, c)] = wreg[nt][r] * fp[c];
      }
    }
    __syncthreads();

    // segmented reduction: 256 threads = 128 cols x 2 row-chunks of 32
    {
      int c = tid & 127;
      int sub = tid >> 7;
      int b0 = sub * 32;
      float acc = 0.0f;
      int cur = sSeg[((b0 >> 4) << 5) + half * 16 + (b0 & 15)];
      for (int b = b0; b < b0 + 32; ++b) {
        int act = ((b >> 4) << 5) + half * 16 + (b & 15);
        int s = sSeg[act];
        if (s != cur) {
          if (cur >= 0) atomicAdd(conv + (size_t)cur * F + c, acc);
          acc = 0.0f; cur = s;
        }
        acc += sWF[wfb_idx(b, c)];
      }
      if (cur >= 0) atomicAdd(conv + (size_t)cur * F + c, acc);
    }
  }
}

// ---------- node pipeline: c = ssp(conv@Wf2o + b); v = c@Wd + b; y = x + v ----------
// weights from global frags; only C staged in LDS (32KB); one sync total
__global__ __launch_bounds__(256, 4) void node_kernel(
    const float* __restrict__ conv, const float* __restrict__ x,
    const float* __restrict__ bf2o, const float* __restrict__ bd,
    const unsigned short* __restrict__ wfrag, float* __restrict__ y,
    float* __restrict__ vout, int N) {
  __shared__ short sC[16384];  // 32KB
  const int tid = threadIdx.x;
  const int lane = tid & 63, wv = tid >> 6;
  const int quad = lane >> 4, ln = lane & 15;
  const int r0 = blockIdx.x * 128;
  const unsigned short* Wa = wfrag + 3 * 16384;
  const unsigned short* Wd = wfrag + 4 * 16384;

  float bfv[8], bdv[8];
#pragma unroll
  for (int nt = 0; nt < 8; ++nt) {
    bfv[nt] = bf2o[nt * 16 + ln];
    bdv[nt] = bd[nt * 16 + ln];
  }

  bf16x8 a1[2][4];
#pragma unroll
  for (int mt = 0; mt < 2; ++mt) {
    int row = r0 + wv * 32 + mt * 16 + ln;
    bool valid = row < N;
    const float* rp = conv + (size_t)row * F + quad * 8;
#pragma unroll
    for (int kb = 0; kb < 4; ++kb) a1[mt][kb] = load_afrag_f32(rp + kb * 32, valid);
  }

#pragma unroll
  for (int nt = 0; nt < 8; ++nt) {
    f32x4 acc0 = {0, 0, 0, 0}, acc1 = {0, 0, 0, 0};
#pragma unroll
    for (int kb = 0; kb < 4; ++kb) {
      bf16x8 b = load_bfrag_g(Wa, nt, kb, lane);
      acc0 = __builtin_amdgcn_mfma_f32_16x16x32_bf16(a1[0][kb], b, acc0, 0, 0, 0);
      acc1 = __builtin_amdgcn_mfma_f32_16x16x32_bf16(a1[1][kb], b, acc1, 0, 0, 0);
    }
    int c = nt * 16 + ln;
#pragma unroll
    for (int r = 0; r < 4; ++r) {
      sC[h_idx(wv * 32 + quad * 4 + r, c)] =
          (short)cvt_pk_bf16(sspf(acc0[r] + bfv[nt]), 0.0f);
      sC[h_idx(wv * 32 + 16 + quad * 4 + r, c)] =
          (short)cvt_pk_bf16(sspf(acc1[r] + bfv[nt]), 0.0f);
    }
  }
  __syncthreads();

  bf16x8 a2[2][4];
#pragma unroll
  for (int mt = 0; mt < 2; ++mt) {
    int row = wv * 32 + mt * 16 + ln;
#pragma unroll
    for (int kb = 0; kb < 4; ++kb)
      a2[mt][kb] = *(const bf16x8*)(sC + h_idx(row, kb * 32 + quad * 8));
  }

#pragma unroll
  for (int nt = 0; nt < 8; ++nt) {
    f32x4 acc0 = {0, 0, 0, 0}, acc1 = {0, 0, 0, 0};
#pragma unroll
    for (int kb = 0; kb < 4; ++kb) {
      bf16x8 b = load_bfrag_g(Wd, nt, kb, lane);
      acc0 = __builtin_amdgcn_mfma_f32_16x16x32_bf16(a2[0][kb], b, acc0, 0, 0, 0);
      acc1 = __builtin_amdgcn_mfma_f32_16x16x32_bf16(a2[1][kb], b, acc1, 0, 0, 0);
    }
    int col = nt * 16 + ln;
#pragma unroll
    for (int mt = 0; mt < 2; ++mt) {
#pragma unroll
      for (int r = 0; r < 4; ++r) {
        int row = r0 + wv * 32 + mt * 16 + quad * 4 + r;
        if (row < N) {
          float v = ((mt == 0) ? acc0[r] : acc1[r]) + bdv[nt];
          size_t o = (size_t)row * F + col;
          y[o] = x[o] + v;
          vout[o] = v;
        }
      }
    }
  }
}

extern "C" void kernel_launch(void* const* d_in, const int* in_sizes, int n_in,
                              void* d_out, int out_size, void* d_ws, size_t ws_size,
                              hipStream_t stream) {
  const float* x    = (const float*)d_in[0];
  const float* dijk = (const float*)d_in[1];
  const int*   idxj = (const int*)d_in[2];
  const int*   segi = (const int*)d_in[3];
  // d_in[4] = seg_j (identity permutation: segment_sum over it is a no-op)
  // d_in[5] = seg_i_sum (== N)
  const float* W1   = (const float*)d_in[6];
  const float* b1   = (const float*)d_in[7];
  const float* W2   = (const float*)d_in[8];
  const float* b2   = (const float*)d_in[9];
  const float* Wi2f = (const float*)d_in[10];
  const float* Wf2o = (const float*)d_in[11];
  const float* bf2o = (const float*)d_in[12];
  const float* Wd   = (const float*)d_in[13];
  const float* bd   = (const float*)d_in[14];

  int N = in_sizes[0] / F;
  int E = in_sizes[1] / F;

  // workspace layout: [5x16384 bf16 weight frags][f: N*F f32][conv: N*F f32]  (~51.4MB)
  unsigned short* wfrag = (unsigned short*)d_ws;
  float* fbuf = (float*)((char*)d_ws + 5 * 16384 * sizeof(unsigned short));
  float* conv = fbuf + (size_t)N * F;

  float* y = (float*)d_out;
  float* vout = y + (size_t)N * F;

  hipMemsetAsync(conv, 0, (size_t)N * F * sizeof(float), stream);
  prep_weights<<<320, 256, 0, stream>>>(W1, W2, Wi2f, Wf2o, Wd, wfrag);

  int nb = (N + 127) / 128;
  int eb = (E + 127) / 128;
  f_kernel<<<nb, 256, 0, stream>>>(x, wfrag, fbuf, N);
  edge_kernel<<<eb, 256, 0, stream>>>(dijk, idxj, segi, b1, b2, wfrag, fbuf, conv, E);
  node_kernel<<<nb, 256, 0, stream>>>(conv, x, bf2o, bd, wfrag, y, vout, N);
}

// Round 3
// 808.580 us; speedup vs baseline: 1.2262x; 1.2262x over previous
//
#include <hip/hip_runtime.h>

#define F 128

typedef __attribute__((ext_vector_type(8))) short bf16x8;
typedef __attribute__((ext_vector_type(4))) float f32x4;

// ---------- helpers ----------

// software RNE f32->bf16 (kept for prep_weights so weight bits are unchanged)
__device__ __forceinline__ short f2bf(float f) {
  union { float f; unsigned u; } v; v.f = f;
  unsigned r = (v.u + 0x7FFFu + ((v.u >> 16) & 1u)) >> 16;  // RNE
  return (short)r;
}

// hardware packed f32->bf16 (RNE), 1 VALU op for 2 converts
__device__ __forceinline__ unsigned cvt_pk_bf16(float a, float b) {
  unsigned d;
  asm("v_cvt_pk_bf16_f32 %0, %1, %2" : "=v"(d) : "v"(a), "v"(b));
  return d;
}

// shifted softplus: softplus(x) - ln(2), numerically stable
__device__ __forceinline__ float sspf(float x) {
  float t = __expf(-fabsf(x));
  return fmaxf(x, 0.0f) + __logf(1.0f + t) - 0.69314718055994530942f;
}

// H/C staging in LDS: 128 rows x 128 bf16, XOR-swizzled in 8-short (16B) chunks
// so that b16 scatter-writes and b128 A-frag reads are both ~conflict-free.
__device__ __forceinline__ int h_idx(int row, int k) {
  int chunk = k >> 3;
  int sw = chunk ^ (row & 15);
  return row * 128 + sw * 8 + (k & 7);
}

// wf half-buffer: 64 rows x 128 f32, bit-4 XOR swizzle breaks the 4-quad conflict
__device__ __forceinline__ int wfb_idx(int row, int c) {
  return row * 128 + (c ^ ((row & 4) << 2));
}

// B-fragment load straight from global frag-ordered weight (L1/L2-hot, coalesced 16B/lane)
__device__ __forceinline__ bf16x8 load_bfrag_g(const unsigned short* __restrict__ W,
                                               int nt, int kb, int lane) {
  return *(const bf16x8*)(W + (((nt * 4 + kb) * 64 + lane) << 3));
}

// A-fragment from row-major fp32 global: 8 consecutive floats -> 8 bf16 (hw cvt_pk)
__device__ __forceinline__ bf16x8 load_afrag_f32(const float* __restrict__ p, bool valid) {
  union { bf16x8 v; unsigned u[4]; } r;
  if (valid) {
    const float4* q = (const float4*)p;
    float4 x0 = q[0], x1 = q[1];
    r.u[0] = cvt_pk_bf16(x0.x, x0.y);
    r.u[1] = cvt_pk_bf16(x0.z, x0.w);
    r.u[2] = cvt_pk_bf16(x1.x, x1.y);
    r.u[3] = cvt_pk_bf16(x1.z, x1.w);
  } else {
    r.u[0] = r.u[1] = r.u[2] = r.u[3] = 0u;
  }
  return r.v;
}

// ---------- prep: convert 5 weight matrices to bf16 MFMA-B-fragment order ----------
// B-frag layout for W[k][n] (128x128): frag(nt,kb), lane = ((k>>3)&3)<<4 | (n&15), j = k&7
__global__ void prep_weights(const float* __restrict__ W1, const float* __restrict__ W2,
                             const float* __restrict__ Wi2f, const float* __restrict__ Wf2o,
                             const float* __restrict__ Wd, unsigned short* __restrict__ out) {
  int t = blockIdx.x * 256 + threadIdx.x;  // 5*16384 total
  int m = t >> 14;
  int idx = t & 16383;
  int k = idx >> 7, n = idx & 127;
  const float* W = (m == 0) ? W1 : (m == 1) ? W2 : (m == 2) ? Wi2f : (m == 3) ? Wf2o : Wd;
  float v = W[idx];
  int nt = n >> 4, kb = k >> 5;
  int lane = (((k >> 3) & 3) << 4) | (n & 15);
  int j = k & 7;
  int dst = (((nt * 4 + kb) * 64 + lane) << 3) | j;
  out[(m << 14) + dst] = (unsigned short)f2bf(v);
}

// ---------- f = x @ W_in2fac  (no bias, no activation; no LDS, no syncs) ----------
// grid is only ~391 blocks (<2/CU): occupancy hint irrelevant, generous VGPR
// cap (256,2) guarantees no scratch spill.
__global__ __launch_bounds__(256, 2) void f_kernel(const float* __restrict__ x,
                                                   const unsigned short* __restrict__ wfrag,
                                                   float* __restrict__ f, int N) {
  const int tid = threadIdx.x;
  const int lane = tid & 63, wv = tid >> 6;
  const int quad = lane >> 4, ln = lane & 15;
  const int r0 = blockIdx.x * 128;
  const unsigned short* Wf = wfrag + 2 * 16384;

  bf16x8 a1[2][4];
#pragma unroll
  for (int mt = 0; mt < 2; ++mt) {
    int row = r0 + wv * 32 + mt * 16 + ln;
    bool valid = row < N;
    const float* rp = x + (size_t)row * F + quad * 8;
#pragma unroll
    for (int kb = 0; kb < 4; ++kb) a1[mt][kb] = load_afrag_f32(rp + kb * 32, valid);
  }

#pragma unroll
  for (int nt = 0; nt < 8; ++nt) {
    f32x4 acc0 = {0, 0, 0, 0}, acc1 = {0, 0, 0, 0};
#pragma unroll
    for (int kb = 0; kb < 4; ++kb) {
      bf16x8 b = load_bfrag_g(Wf, nt, kb, lane);
      acc0 = __builtin_amdgcn_mfma_f32_16x16x32_bf16(a1[0][kb], b, acc0, 0, 0, 0);
      acc1 = __builtin_amdgcn_mfma_f32_16x16x32_bf16(a1[1][kb], b, acc1, 0, 0, 0);
    }
    int col = nt * 16 + ln;
#pragma unroll
    for (int mt = 0; mt < 2; ++mt) {
#pragma unroll
      for (int r = 0; r < 4; ++r) {
        int row = r0 + wv * 32 + mt * 16 + quad * 4 + r;
        if (row < N) f[(size_t)row * F + col] = (mt == 0) ? acc0[r] : acc1[r];
      }
    }
  }
}

// ---------- fused edge pipeline ----------
// h = ssp(dijk@W1+b1); w = ssp(h@W2+b2); (seg_j = arange -> identity)
// wf = w * f[idx_j]; conv[seg_i] += wf  (seg_i sorted -> run-length reduce + atomics)
// LDS: 32KB union {H bf16 128x128 | wf f32 64x128 half-tile}.
// launch_bounds(256,3): VGPR budget 168. Rounds 1-2 used (256,4) (cap 128):
// the unrolled nt-loops let the scheduler hoist global B-frag loads past the
// ~130-reg live set, overflowing the cap -> 240-340MB/launch scratch spill
// traffic (WRITE_SIZE 272-366MB vs ~31MB of real atomics). Budget 168 fits
// live set + bounded hoisting with zero memory spills; occupancy 3 blocks/CU.
__global__ __launch_bounds__(256, 3) void edge_kernel(
    const float* __restrict__ dijk, const int* __restrict__ idx_j, const int* __restrict__ seg_i,
    const float* __restrict__ b1, const float* __restrict__ b2,
    const unsigned short* __restrict__ wfrag, const float* __restrict__ f,
    float* __restrict__ conv, int E) {
  __shared__ union { short s[16384]; float fl[8192]; } sm;  // 32KB
  __shared__ int sIdx[128];
  __shared__ int sSeg[128];

  const int tid = threadIdx.x;
  const int lane = tid & 63, wv = tid >> 6;
  const int quad = lane >> 4, ln = lane & 15;
  const int e0 = blockIdx.x * 128;
  const unsigned short* W1f = wfrag;
  const unsigned short* W2f = wfrag + 16384;

  if (tid < 128) {
    int e = e0 + tid;
    sIdx[tid] = (e < E) ? idx_j[e] : 0;
    sSeg[tid] = (e < E) ? seg_i[e] : -1;
  }

  float bias1v[8], bias2v[8];
#pragma unroll
  for (int nt = 0; nt < 8; ++nt) {
    bias1v[nt] = b1[nt * 16 + ln];
    bias2v[nt] = b2[nt * 16 + ln];
  }

  // A1 frags straight from global dijk (each wave owns 32 edge rows)
  bf16x8 a1[2][4];
#pragma unroll
  for (int mt = 0; mt < 2; ++mt) {
    int row = e0 + wv * 32 + mt * 16 + ln;
    bool valid = row < E;
    const float* rp = dijk + (size_t)row * F + quad * 8;
#pragma unroll
    for (int kb = 0; kb < 4; ++kb) a1[mt][kb] = load_afrag_f32(rp + kb * 32, valid);
  }

  // GEMM1 (B-frags from global) -> ssp -> bf16 -> sH directly
  short* sH = sm.s;
#pragma unroll
  for (int nt = 0; nt < 8; ++nt) {
    f32x4 acc0 = {0, 0, 0, 0}, acc1 = {0, 0, 0, 0};
#pragma unroll
    for (int kb = 0; kb < 4; ++kb) {
      bf16x8 b = load_bfrag_g(W1f, nt, kb, lane);
      acc0 = __builtin_amdgcn_mfma_f32_16x16x32_bf16(a1[0][kb], b, acc0, 0, 0, 0);
      acc1 = __builtin_amdgcn_mfma_f32_16x16x32_bf16(a1[1][kb], b, acc1, 0, 0, 0);
    }
    int c = nt * 16 + ln;
#pragma unroll
    for (int r = 0; r < 4; ++r) {
      sH[h_idx(wv * 32 + quad * 4 + r, c)] =
          (short)cvt_pk_bf16(sspf(acc0[r] + bias1v[nt]), 0.0f);
      sH[h_idx(wv * 32 + 16 + quad * 4 + r, c)] =
          (short)cvt_pk_bf16(sspf(acc1[r] + bias1v[nt]), 0.0f);
    }
  }
  __syncthreads();

  // GEMM2 A frags from staged H (both halves; sH dies after this)
  bf16x8 a2[2][4];
#pragma unroll
  for (int mt = 0; mt < 2; ++mt) {
    int row = wv * 32 + mt * 16 + ln;
#pragma unroll
    for (int kb = 0; kb < 4; ++kb)
      a2[mt][kb] = *(const bf16x8*)(sH + h_idx(row, kb * 32 + quad * 8));
  }

  // GEMM2 single-pass (both halves): wreg[2][8][4] = 64 f32 live, fits the
  // 168-reg budget without spilling; fewer barriers than the two-pass split.
  float wreg[2][8][4];
#pragma unroll
  for (int nt = 0; nt < 8; ++nt) {
    f32x4 acc0 = {0, 0, 0, 0}, acc1 = {0, 0, 0, 0};
#pragma unroll
    for (int kb = 0; kb < 4; ++kb) {
      bf16x8 b = load_bfrag_g(W2f, nt, kb, lane);
      acc0 = __builtin_amdgcn_mfma_f32_16x16x32_bf16(a2[0][kb], b, acc0, 0, 0, 0);
      acc1 = __builtin_amdgcn_mfma_f32_16x16x32_bf16(a2[1][kb], b, acc1, 0, 0, 0);
    }
#pragma unroll
    for (int r = 0; r < 4; ++r) {
      wreg[0][nt][r] = sspf(acc0[r] + bias2v[nt]);
      wreg[1][nt][r] = sspf(acc1[r] + bias2v[nt]);
    }
  }
  __syncthreads();  // all sH reads done before wf half-tile overwrites it

  // wf = w * f[idx_j], processed in two 64-row halves (half = mt) so the tile
  // fits in 32KB. All 4 waves write each half (wave wv's mt-half rows map to
  // buffer rows wv*16 + quad*4 + r). Run-length merging across the 16-row gaps
  // is fine: addition into conv[seg] is order/partition independent.
  float* sWF = sm.fl;
#pragma unroll
  for (int half = 0; half < 2; ++half) {
#pragma unroll
    for (int r = 0; r < 4; ++r) {
      int lr = quad * 4 + r;
      int brow = wv * 16 + lr;
      int erow = wv * 32 + half * 16 + lr;
      int jrow = sIdx[erow];
      const float* fp = f + (size_t)jrow * F;
#pragma unroll
      for (int nt = 0; nt < 8; ++nt) {
        int c = nt * 16 + ln;
        sWF[wfb_idx(brow, c)] = wreg[half][nt][r] * fp[c];
      }
    }
    __syncthreads();

    // segmented reduction: 256 threads = 128 cols x 2 row-chunks of 32
    {
      int c = tid & 127;
      int sub = tid >> 7;
      int b0 = sub * 32;
      float acc = 0.0f;
      int cur = sSeg[((b0 >> 4) << 5) + half * 16 + (b0 & 15)];
      for (int b = b0; b < b0 + 32; ++b) {
        int act = ((b >> 4) << 5) + half * 16 + (b & 15);
        int s = sSeg[act];
        if (s != cur) {
          if (cur >= 0) atomicAdd(conv + (size_t)cur * F + c, acc);
          acc = 0.0f; cur = s;
        }
        acc += sWF[wfb_idx(b, c)];
      }
      if (cur >= 0) atomicAdd(conv + (size_t)cur * F + c, acc);
    }
    if (half == 0) __syncthreads();  // half-0 reduce done before half-1 overwrites
  }
}

// ---------- node pipeline: c = ssp(conv@Wf2o + b); v = c@Wd + b; y = x + v ----------
// weights from global frags; only C staged in LDS (32KB); one sync total.
// grid ~391 blocks: occupancy hint irrelevant, (256,2) avoids any spill.
__global__ __launch_bounds__(256, 2) void node_kernel(
    const float* __restrict__ conv, const float* __restrict__ x,
    const float* __restrict__ bf2o, const float* __restrict__ bd,
    const unsigned short* __restrict__ wfrag, float* __restrict__ y,
    float* __restrict__ vout, int N) {
  __shared__ short sC[16384];  // 32KB
  const int tid = threadIdx.x;
  const int lane = tid & 63, wv = tid >> 6;
  const int quad = lane >> 4, ln = lane & 15;
  const int r0 = blockIdx.x * 128;
  const unsigned short* Wa = wfrag + 3 * 16384;
  const unsigned short* Wd = wfrag + 4 * 16384;

  float bfv[8], bdv[8];
#pragma unroll
  for (int nt = 0; nt < 8; ++nt) {
    bfv[nt] = bf2o[nt * 16 + ln];
    bdv[nt] = bd[nt * 16 + ln];
  }

  bf16x8 a1[2][4];
#pragma unroll
  for (int mt = 0; mt < 2; ++mt) {
    int row = r0 + wv * 32 + mt * 16 + ln;
    bool valid = row < N;
    const float* rp = conv + (size_t)row * F + quad * 8;
#pragma unroll
    for (int kb = 0; kb < 4; ++kb) a1[mt][kb] = load_afrag_f32(rp + kb * 32, valid);
  }

#pragma unroll
  for (int nt = 0; nt < 8; ++nt) {
    f32x4 acc0 = {0, 0, 0, 0}, acc1 = {0, 0, 0, 0};
#pragma unroll
    for (int kb = 0; kb < 4; ++kb) {
      bf16x8 b = load_bfrag_g(Wa, nt, kb, lane);
      acc0 = __builtin_amdgcn_mfma_f32_16x16x32_bf16(a1[0][kb], b, acc0, 0, 0, 0);
      acc1 = __builtin_amdgcn_mfma_f32_16x16x32_bf16(a1[1][kb], b, acc1, 0, 0, 0);
    }
    int c = nt * 16 + ln;
#pragma unroll
    for (int r = 0; r < 4; ++r) {
      sC[h_idx(wv * 32 + quad * 4 + r, c)] =
          (short)cvt_pk_bf16(sspf(acc0[r] + bfv[nt]), 0.0f);
      sC[h_idx(wv * 32 + 16 + quad * 4 + r, c)] =
          (short)cvt_pk_bf16(sspf(acc1[r] + bfv[nt]), 0.0f);
    }
  }
  __syncthreads();

  bf16x8 a2[2][4];
#pragma unroll
  for (int mt = 0; mt < 2; ++mt) {
    int row = wv * 32 + mt * 16 + ln;
#pragma unroll
    for (int kb = 0; kb < 4; ++kb)
      a2[mt][kb] = *(const bf16x8*)(sC + h_idx(row, kb * 32 + quad * 8));
  }

#pragma unroll
  for (int nt = 0; nt < 8; ++nt) {
    f32x4 acc0 = {0, 0, 0, 0}, acc1 = {0, 0, 0, 0};
#pragma unroll
    for (int kb = 0; kb < 4; ++kb) {
      bf16x8 b = load_bfrag_g(Wd, nt, kb, lane);
      acc0 = __builtin_amdgcn_mfma_f32_16x16x32_bf16(a2[0][kb], b, acc0, 0, 0, 0);
      acc1 = __builtin_amdgcn_mfma_f32_16x16x32_bf16(a2[1][kb], b, acc1, 0, 0, 0);
    }
    int col = nt * 16 + ln;
#pragma unroll
    for (int mt = 0; mt < 2; ++mt) {
#pragma unroll
      for (int r = 0; r < 4; ++r) {
        int row = r0 + wv * 32 + mt * 16 + quad * 4 + r;
        if (row < N) {
          float v = ((mt == 0) ? acc0[r] : acc1[r]) + bdv[nt];
          size_t o = (size_t)row * F + col;
          y[o] = x[o] + v;
          vout[o] = v;
        }
      }
    }
  }
}

extern "C" void kernel_launch(void* const* d_in, const int* in_sizes, int n_in,
                              void* d_out, int out_size, void* d_ws, size_t ws_size,
                              hipStream_t stream) {
  const float* x    = (const float*)d_in[0];
  const float* dijk = (const float*)d_in[1];
  const int*   idxj = (const int*)d_in[2];
  const int*   segi = (const int*)d_in[3];
  // d_in[4] = seg_j (identity permutation: segment_sum over it is a no-op)
  // d_in[5] = seg_i_sum (== N)
  const float* W1   = (const float*)d_in[6];
  const float* b1   = (const float*)d_in[7];
  const float* W2   = (const float*)d_in[8];
  const float* b2   = (const float*)d_in[9];
  const float* Wi2f = (const float*)d_in[10];
  const float* Wf2o = (const float*)d_in[11];
  const float* bf2o = (const float*)d_in[12];
  const float* Wd   = (const float*)d_in[13];
  const float* bd   = (const float*)d_in[14];

  int N = in_sizes[0] / F;
  int E = in_sizes[1] / F;

  // workspace layout: [5x16384 bf16 weight frags][f: N*F f32][conv: N*F f32]  (~51.4MB)
  unsigned short* wfrag = (unsigned short*)d_ws;
  float* fbuf = (float*)((char*)d_ws + 5 * 16384 * sizeof(unsigned short));
  float* conv = fbuf + (size_t)N * F;

  float* y = (float*)d_out;
  float* vout = y + (size_t)N * F;

  hipMemsetAsync(conv, 0, (size_t)N * F * sizeof(float), stream);
  prep_weights<<<320, 256, 0, stream>>>(W1, W2, Wi2f, Wf2o, Wd, wfrag);

  int nb = (N + 127) / 128;
  int eb = (E + 127) / 128;
  f_kernel<<<nb, 256, 0, stream>>>(x, wfrag, fbuf, N);
  edge_kernel<<<eb, 256, 0, stream>>>(dijk, idxj, segi, b1, b2, wfrag, fbuf, conv, E);
  node_kernel<<<nb, 256, 0, stream>>>(conv, x, bf2o, bd, wfrag, y, vout, N);
}